// Round 5
// baseline (381.284 us; speedup 1.0000x reference)
//
#include <hip/hip_runtime.h>
#include <stdint.h>

#define NB 4096          // coarse buckets (top 12 bits of monotone key)
#define BSH 20
#define RSH 14           // refined buckets: 64x finer
#define HS 512
#define HM 511
#define CAP 4096         // candidate capacity
#define PCAP 2048        // pruned-candidate capacity
#define NRB 2048         // refined buckets
#define NT 1024

typedef unsigned long long ull;

// ---- monotonic float<->uint mapping: larger float => larger uint ----
__device__ __forceinline__ unsigned mono_u32(float x) {
    unsigned b = __float_as_uint(x);
    return (b & 0x80000000u) ? ~b : (b | 0x80000000u);
}
__device__ __forceinline__ float inv_mono(unsigned u) {
    unsigned b = (u & 0x80000000u) ? (u & 0x7fffffffu) : ~u;
    return __uint_as_float(b);
}

// numpy op order: pen = freq*cnt + pres*(cnt>0); x = (l - pen) / t
__device__ __forceinline__ float compute_x(float l, int cnt,
                                           float pres, float freq, float t) {
    float pen = __fadd_rn(__fmul_rn(freq, (float)cnt), (cnt > 0) ? pres : 0.0f);
    return __fdiv_rn(__fsub_rn(l, pen), t);
}

__device__ __forceinline__ int hash_lookup(const int* hkey, const int* hval, int v) {
    unsigned h = ((unsigned)v * 2654435761u) >> 23;
    while (true) {
        int kk = hkey[h];
        if (kk == v) return hval[h];
        if (kk == -1) return 0;
        h = (h + 1) & HM;
    }
}

// destructive suffix scan over NB buckets; returns max b with suffix>=k, or -1
__device__ int suffix_cut(unsigned* hc, int* sct, int* sct2, int k, int tid, int* sh) {
    if (tid == 0) *sh = -1;
    const int BPT = NB / NT;   // 4
    int base = tid * BPT;
    int acc = 0;
#pragma unroll
    for (int q = BPT - 1; q >= 0; --q) { acc += (int)hc[base + q]; hc[base + q] = (unsigned)acc; }
    sct[tid] = acc;
    __syncthreads();
    int* a = sct; int* b2 = sct2;
    for (int s = 1; s < NT; s <<= 1) {
        int v = a[tid] + ((tid + s < NT) ? a[tid + s] : 0);
        __syncthreads();
        b2[tid] = v;
        __syncthreads();
        int* tmp = a; a = b2; b2 = tmp;
    }
    int above = (tid < NT - 1) ? a[tid + 1] : 0;
    int best = -1;
#pragma unroll
    for (int q = BPT - 1; q >= 0; --q)
        if ((int)hc[base + q] + above >= k) { best = base + q; break; }
    if (best >= 0) atomicMax(sh, best);
    __syncthreads();
    int r = *sh;
    __syncthreads();
    return r;
}

__global__ __launch_bounds__(NT) void k_fused(
    const float* __restrict__ logits, const int* __restrict__ tokens,
    const float* __restrict__ pres_v, const float* __restrict__ freq_v,
    const float* __restrict__ temps, const float* __restrict__ topp_v,
    const int* __restrict__ topk_v, int V, int H, float* __restrict__ out)
{
    __shared__ ull skey[CAP];                 // 32 KB: candidates
    __shared__ ull hreg[2048];                // 16 KB: hc / rh / tmpc / se
    __shared__ int sct[NT], sct2[NT];         // 8 KB: scan scratch (+bs alias)
    __shared__ int hkey[HS], hval[HS];        // 4 KB: penalty hash
    __shared__ float esum_s, corr_s;
    __shared__ int cut_s, lcnt_s, rb_s, pcnt_s;

    unsigned* hc = (unsigned*)hreg;           // 4096 u32
    unsigned* rh = (unsigned*)hreg;           // 2048 u32 (after hc dead)
    ull* tmpc = hreg;                         // 2048 u64 (after rh dead)
    float* se = (float*)hreg;                 // 4096 f32 (after tmpc dead)
    float* bs1 = (float*)sct;
    float* bs2 = (float*)sct2;

    int row = blockIdx.x, tid = threadIdx.x;
    for (int b = tid; b < NB; b += NT) hc[b] = 0u;
    for (int i = tid; i < HS; i += NT) { hkey[i] = -1; hval[i] = 0; }
    if (tid == 0) { esum_s = 0.f; corr_s = 0.f; lcnt_s = 0; rb_s = 0; pcnt_s = 0; }
    __syncthreads();

    // ---- build penalty-token hash ----
    const int* trow = tokens + (size_t)row * H;
    for (int i = tid; i < H; i += NT) {
        int v = trow[i];
        unsigned h = ((unsigned)v * 2654435761u) >> 23;
        while (true) {
            int prev = atomicCAS(&hkey[h], -1, v);
            if (prev == -1 || prev == v) { atomicAdd(&hval[h], 1); break; }
            h = (h + 1) & HM;
        }
    }

    float t = temps[row];
    float r = __fdiv_rn(1.0f, t);     // same approx everywhere
    float pres = pres_v[row], freq = freq_v[row];
    int active = (pres >= 1e-5f) || (freq >= 1e-5f);
    int k = topk_v[row];
    const float* lrow = logits + (size_t)row * V;
    const float4* l4p = (const float4*)lrow;
    int V4 = V >> 2;
    __syncthreads();

    // ---- Phase S: sampled histogram (1/16 of elements, jittered) ----
    int S4 = V4 >> 4;
    for (int s = tid; s < S4; s += NT) {
        float4 A = l4p[(s << 4) + (s & 15)];
#pragma unroll
        for (int j = 0; j < 4; ++j)
            atomicAdd(&hc[mono_u32(__fmul_rn((&A.x)[j], r)) >> BSH], 1u);
    }
    __syncthreads();
    float ms = (S4 > 0) ? ((float)k * (float)(S4 << 2) / (float)V) : 0.0f;
    int req = (int)(ms + 8.0f * sqrtf(ms) + 16.0f);
    int bT = (S4 > 0) ? suffix_cut(hc, sct, sct2, req, tid, &cut_s) : 0;
    int thr = bT - 1; if (thr < 0) thr = 0;
    for (int b = tid; b < NB; b += NT) hc[b] = 0u;
    __syncthreads();

    // ---- Phase A: single stream — zero-out + Sexp + sparse hist + compact ----
    float4* o4p = (float4*)(out + (size_t)row * V);
    const float4 z4 = make_float4(0.f, 0.f, 0.f, 0.f);
    float es0 = 0.f, es1 = 0.f, es2 = 0.f, es3 = 0.f;
    int i = tid;
    for (; i + 7 * NT < V4; i += 8 * NT) {
        float4 arr[8];
#pragma unroll
        for (int q = 0; q < 8; ++q) arr[q] = l4p[i + q * NT];
#pragma unroll
        for (int q = 0; q < 8; ++q) o4p[i + q * NT] = z4;
#pragma unroll
        for (int q = 0; q < 8; ++q) {
            int vb = (i + q * NT) << 2;
            float x0 = __fmul_rn(arr[q].x, r), x1 = __fmul_rn(arr[q].y, r);
            float x2 = __fmul_rn(arr[q].z, r), x3 = __fmul_rn(arr[q].w, r);
            es0 += __expf(x0); es1 += __expf(x1); es2 += __expf(x2); es3 += __expf(x3);
            unsigned u0 = mono_u32(x0), u1 = mono_u32(x1);
            unsigned u2 = mono_u32(x2), u3 = mono_u32(x3);
            if ((int)(u0 >> BSH) >= thr) {
                atomicAdd(&hc[u0 >> BSH], 1u);
                int pos = atomicAdd(&lcnt_s, 1);
                if (pos < CAP) skey[pos] = ((ull)u0 << 32) | (unsigned)~(unsigned)(vb);
            }
            if ((int)(u1 >> BSH) >= thr) {
                atomicAdd(&hc[u1 >> BSH], 1u);
                int pos = atomicAdd(&lcnt_s, 1);
                if (pos < CAP) skey[pos] = ((ull)u1 << 32) | (unsigned)~(unsigned)(vb + 1);
            }
            if ((int)(u2 >> BSH) >= thr) {
                atomicAdd(&hc[u2 >> BSH], 1u);
                int pos = atomicAdd(&lcnt_s, 1);
                if (pos < CAP) skey[pos] = ((ull)u2 << 32) | (unsigned)~(unsigned)(vb + 2);
            }
            if ((int)(u3 >> BSH) >= thr) {
                atomicAdd(&hc[u3 >> BSH], 1u);
                int pos = atomicAdd(&lcnt_s, 1);
                if (pos < CAP) skey[pos] = ((ull)u3 << 32) | (unsigned)~(unsigned)(vb + 3);
            }
        }
    }
    for (; i < V4; i += NT) {
        float4 A = l4p[i];
        o4p[i] = z4;
#pragma unroll
        for (int j = 0; j < 4; ++j) {
            float x = __fmul_rn((&A.x)[j], r);
            es0 += __expf(x);
            unsigned u = mono_u32(x);
            if ((int)(u >> BSH) >= thr) {
                atomicAdd(&hc[u >> BSH], 1u);
                int pos = atomicAdd(&lcnt_s, 1);
                if (pos < CAP) skey[pos] = ((ull)u << 32) | (unsigned)~(unsigned)((i << 2) + j);
            }
        }
    }
    for (int v = (V4 << 2) + tid; v < V; v += NT) {
        float x = __fmul_rn(lrow[v], r);
        out[(size_t)row * V + v] = 0.0f;
        es0 += __expf(x);
        unsigned u = mono_u32(x);
        if ((int)(u >> BSH) >= thr) {
            atomicAdd(&hc[u >> BSH], 1u);
            int pos = atomicAdd(&lcnt_s, 1);
            if (pos < CAP) skey[pos] = ((ull)u << 32) | (unsigned)~(unsigned)v;
        }
    }
    float es = (es0 + es1) + (es2 + es3);
    for (int off = 32; off; off >>= 1) es += __shfl_down(es, off);
    if ((tid & 63) == 0) atomicAdd(&esum_s, es);
    __syncthreads();

    // ---- penalty corrections: hist moves + Sexp delta ----
    float corr = 0.0f;
    if (active) {
        for (int s = tid; s < HS; s += NT) {
            int v = hkey[s];
            if (v >= 0) {
                int c = hval[s];
                float l = lrow[v];
                float x0 = __fmul_rn(l, r);
                float xp = compute_x(l, c, pres, freq, t);
                int b0 = (int)(mono_u32(x0) >> BSH);
                int bp = (int)(mono_u32(xp) >> BSH);
                if (b0 != bp) {
                    if (b0 >= thr) atomicSub(&hc[b0], 1u);
                    if (bp >= thr) atomicAdd(&hc[bp], 1u);
                }
                corr += __expf(xp) - __expf(x0);
            }
        }
    }
    for (int off = 32; off; off >>= 1) corr += __shfl_down(corr, off);
    if ((tid & 63) == 0) atomicAdd(&corr_s, corr);
    __syncthreads();
    int lraw = lcnt_s;
    int count = lraw > CAP ? CAP : lraw;

    // ---- key fix-up: exact (penalized) keys for candidates ----
    for (int j = tid; j < count; j += NT) {
        unsigned idx = ~(unsigned)(skey[j] & 0xffffffffull);
        float l = lrow[idx];
        int c = active ? hash_lookup(hkey, hval, (int)idx) : 0;
        unsigned ue = (c > 0) ? mono_u32(compute_x(l, c, pres, freq, t))
                              : mono_u32(__fdiv_rn(l, t));
        skey[j] = ((ull)ue << 32) | (unsigned)~idx;
    }
    __syncthreads();

    int bst = suffix_cut(hc, sct, sct2, k, tid, &cut_s);
    bool ok = (bst >= thr + 1) && (lraw <= CAP);

    if (!ok) {
        // ---- fallback: exact full-histogram path (cold) ----
        for (int b = tid; b < NB; b += NT) hc[b] = 0u;
        if (tid == 0) lcnt_s = 0;
        __syncthreads();
        for (int v = tid; v < V; v += NT)
            atomicAdd(&hc[mono_u32(__fmul_rn(lrow[v], r)) >> BSH], 1u);
        __syncthreads();
        if (active) {
            for (int s = tid; s < HS; s += NT) {
                int v = hkey[s];
                if (v >= 0) {
                    int c = hval[s];
                    float l = lrow[v];
                    int b0 = (int)(mono_u32(__fmul_rn(l, r)) >> BSH);
                    int bp = (int)(mono_u32(compute_x(l, c, pres, freq, t)) >> BSH);
                    if (b0 != bp) { atomicSub(&hc[b0], 1u); atomicAdd(&hc[bp], 1u); }
                }
            }
        }
        __syncthreads();
        bst = suffix_cut(hc, sct, sct2, k, tid, &cut_s);
        int thr2 = bst - 1; if (thr2 < 0) thr2 = 0;
        for (int v = tid; v < V; v += NT) {
            unsigned u = mono_u32(__fmul_rn(lrow[v], r));
            if ((int)(u >> BSH) >= thr2) {
                int pos = atomicAdd(&lcnt_s, 1);
                if (pos < CAP) skey[pos] = ((ull)u << 32) | (unsigned)~(unsigned)v;
            }
        }
        __syncthreads();
        count = lcnt_s > CAP ? CAP : lcnt_s;
        for (int j = tid; j < count; j += NT) {
            unsigned idx = ~(unsigned)(skey[j] & 0xffffffffull);
            float l = lrow[idx];
            int c = active ? hash_lookup(hkey, hval, (int)idx) : 0;
            unsigned ue = (c > 0) ? mono_u32(compute_x(l, c, pres, freq, t))
                                  : mono_u32(__fdiv_rn(l, t));
            skey[j] = ((ull)ue << 32) | (unsigned)~idx;
        }
        __syncthreads();
    }
    float Sp = esum_s + corr_s;

    // ---- Phase D: refined cut on exact keys + prune ----
    for (int g = tid; g < NRB; g += NT) rh[g] = 0u;
    __syncthreads();
    int gmin = (bst - 1) << 6;
    for (int j = tid; j < count; j += NT) {
        unsigned u = (unsigned)(skey[j] >> 32);
        int rel = (int)(u >> RSH) - gmin;
        rel = rel < 0 ? 0 : (rel > NRB - 1 ? NRB - 1 : rel);
        atomicAdd(&rh[rel], 1u);
    }
    __syncthreads();
    {
        int b2i = tid * 2;
        int a2 = (int)rh[b2i + 1];
        rh[b2i + 1] = (unsigned)a2;
        a2 += (int)rh[b2i];
        rh[b2i] = (unsigned)a2;
        sct[tid] = a2;
        __syncthreads();
        int* a = sct; int* b2 = sct2;
        for (int s = 1; s < NT; s <<= 1) {
            int v = a[tid] + ((tid + s < NT) ? a[tid + s] : 0);
            __syncthreads();
            b2[tid] = v;
            __syncthreads();
            int* tmp = a; a = b2; b2 = tmp;
        }
        int above = (tid < NT - 1) ? a[tid + 1] : 0;
        int best = -1;
        if ((int)rh[b2i + 1] + above >= k) best = b2i + 1;
        else if ((int)rh[b2i] + above >= k) best = b2i;
        if (best >= 0) atomicMax(&rb_s, best);
    }
    __syncthreads();
    int rb = rb_s;
    for (int j = tid; j < count; j += NT) {
        unsigned u = (unsigned)(skey[j] >> 32);
        int rel = (int)(u >> RSH) - gmin;
        rel = rel < 0 ? 0 : (rel > NRB - 1 ? NRB - 1 : rel);
        if (rel >= rb) {
            int pos = atomicAdd(&pcnt_s, 1);
            if (pos < PCAP) tmpc[pos] = skey[j];
        }
    }
    __syncthreads();
    int count2 = pcnt_s;
    if (count2 <= PCAP) {
        for (int j = tid; j < count2; j += NT) skey[j] = tmpc[j];
        count = count2;
    }
    __syncthreads();

    // ---- Phase E: bitonic sort descending on (u desc, idx asc) ----
    int m = 1; while (m < count) m <<= 1;
    for (int j = count + tid; j < m; j += NT) skey[j] = 0ull;
    __syncthreads();
    for (int kk = 2; kk <= m; kk <<= 1) {
        for (int jj = kk >> 1; jj > 0; jj >>= 1) {
            for (int i2 = tid; i2 < m; i2 += NT) {
                int ixj = i2 ^ jj;
                if (ixj > i2) {
                    ull A = skey[i2], B = skey[ixj];
                    bool up = ((i2 & kk) != 0);
                    if ((A > B) == up) { skey[i2] = B; skey[ixj] = A; }
                }
            }
            __syncthreads();
        }
    }

    // ---- Phase F: exp, exact cumsum, top-k/top-p select, scatter ----
    for (int j = tid; j < CAP; j += NT)
        se[j] = (j < count) ? __expf(inv_mono((unsigned)(skey[j] >> 32))) : 0.0f;
    __syncthreads();
    int j0 = tid << 2;
    float e0 = se[j0], e1 = se[j0 + 1], e2 = se[j0 + 2], e3 = se[j0 + 3];
    float c0 = e0, c1 = c0 + e1, c2 = c1 + e2, c3 = c2 + e3;
    __syncthreads();   // se reads done before bs1 (sct alias) writes? separate regions — bs aliases sct, fine
    bs1[tid] = c3;
    __syncthreads();
    float* a = bs1; float* b2 = bs2;
    for (int s = 1; s < NT; s <<= 1) {
        float v = a[tid] + ((tid >= s) ? a[tid - s] : 0.0f);
        __syncthreads();
        b2[tid] = v;
        __syncthreads();
        float* tmp = a; a = b2; b2 = tmp;
    }
    float pre = (tid > 0) ? a[tid - 1] : 0.0f;

    float pS = topp_v[row] * Sp;
    float inc[4] = {pre + c0, pre + c1, pre + c2, pre + c3};
    float ee[4] = {e0, e1, e2, e3};
#pragma unroll
    for (int q = 0; q < 4; ++q) {
        int j = j0 + q;
        if (j < count) {
            float e = ee[q];
            float excl = __fsub_rn(inc[q], e);
            if ((j < k) && (excl <= pS)) {
                unsigned idx = ~(unsigned)(skey[j] & 0xffffffffull);
                out[(size_t)row * V + idx] = __fdiv_rn(e, Sp);
            }
        }
    }
}

extern "C" void kernel_launch(void* const* d_in, const int* in_sizes, int n_in,
                              void* d_out, int out_size, void* d_ws, size_t ws_size,
                              hipStream_t stream) {
    const float* logits = (const float*)d_in[0];
    const float* pres   = (const float*)d_in[1];
    const float* freq   = (const float*)d_in[2];
    const float* temps  = (const float*)d_in[3];
    const float* topps  = (const float*)d_in[4];
    const int*   tokens = (const int*)d_in[5];
    const int*   topks  = (const int*)d_in[6];
    int N = in_sizes[1];
    int V = in_sizes[0] / N;
    int H = in_sizes[5] / N;
    float* out = (float*)d_out;

    k_fused<<<N, NT, 0, stream>>>(logits, tokens, pres, freq, temps, topps,
                                  topks, V, H, out);
}

// Round 6
// 303.717 us; speedup vs baseline: 1.2554x; 1.2554x over previous
//
#include <hip/hip_runtime.h>
#include <stdint.h>

#define NB 4096          // coarse buckets (top 12 bits of monotone key)
#define BSH 20
#define RSH 14           // refined buckets: 64x finer
#define HS 512
#define HM 511
#define CAP 8192         // candidate capacity (overflow ~impossible)
#define PCAP 4096        // pruned-candidate capacity
#define NRB 2048         // refined buckets
#define NT 1024

typedef unsigned long long ull;

// ---- monotonic float<->uint mapping: larger float => larger uint ----
__device__ __forceinline__ unsigned mono_u32(float x) {
    unsigned b = __float_as_uint(x);
    return (b & 0x80000000u) ? ~b : (b | 0x80000000u);
}
__device__ __forceinline__ float inv_mono(unsigned u) {
    unsigned b = (u & 0x80000000u) ? (u & 0x7fffffffu) : ~u;
    return __uint_as_float(b);
}

// numpy op order: pen = freq*cnt + pres*(cnt>0); x = (l - pen) / t
__device__ __forceinline__ float compute_x(float l, int cnt,
                                           float pres, float freq, float t) {
    float pen = __fadd_rn(__fmul_rn(freq, (float)cnt), (cnt > 0) ? pres : 0.0f);
    return __fdiv_rn(__fsub_rn(l, pen), t);
}

__device__ __forceinline__ int hash_lookup(const int* hkey, const int* hval, int v) {
    unsigned h = ((unsigned)v * 2654435761u) >> 23;
    while (true) {
        int kk = hkey[h];
        if (kk == v) return hval[h];
        if (kk == -1) return 0;
        h = (h + 1) & HM;
    }
}

// destructive suffix scan over NB buckets; returns max b with suffix>=k, or -1
__device__ int suffix_cut(unsigned* hc, int* sct, int* sct2, int k, int tid, int* sh) {
    if (tid == 0) *sh = -1;
    const int BPT = NB / NT;   // 4
    int base = tid * BPT;
    int acc = 0;
#pragma unroll
    for (int q = BPT - 1; q >= 0; --q) { acc += (int)hc[base + q]; hc[base + q] = (unsigned)acc; }
    sct[tid] = acc;
    __syncthreads();
    int* a = sct; int* b2 = sct2;
    for (int s = 1; s < NT; s <<= 1) {
        int v = a[tid] + ((tid + s < NT) ? a[tid + s] : 0);
        __syncthreads();
        b2[tid] = v;
        __syncthreads();
        int* tmp = a; a = b2; b2 = tmp;
    }
    int above = (tid < NT - 1) ? a[tid + 1] : 0;
    int best = -1;
#pragma unroll
    for (int q = BPT - 1; q >= 0; --q)
        if ((int)hc[base + q] + above >= k) { best = base + q; break; }
    if (best >= 0) atomicMax(sh, best);
    __syncthreads();
    int r = *sh;
    __syncthreads();
    return r;
}

__global__ __launch_bounds__(NT) void k_fused(
    const float* __restrict__ logits, const int* __restrict__ tokens,
    const float* __restrict__ pres_v, const float* __restrict__ freq_v,
    const float* __restrict__ temps, const float* __restrict__ topp_v,
    const int* __restrict__ topk_v, int V, int H, float* __restrict__ out)
{
    __shared__ ull skey[CAP];                 // 64 KB: candidates
    __shared__ ull hreg[4096];                // 32 KB: hc / rh / tmpc / se
    __shared__ int sct[NT], sct2[NT];         // 8 KB: scan scratch (+bs alias)
    __shared__ int hkey[HS], hval[HS];        // 4 KB: penalty hash
    __shared__ float esum_s, corr_s;
    __shared__ int cut_s, lcnt_s, rb_s, pcnt_s;

    unsigned* hc = (unsigned*)hreg;           // 4096 u32
    unsigned* rh = (unsigned*)hreg;           // 2048 u32 (after hc dead)
    ull* tmpc = hreg;                         // 4096 u64 (after rh dead)
    float* se = (float*)hreg;                 // 8192 f32 (after tmpc dead)
    float* bs1 = (float*)sct;
    float* bs2 = (float*)sct2;

    int row = blockIdx.x, tid = threadIdx.x;
    for (int b = tid; b < NB; b += NT) hc[b] = 0u;
    for (int i = tid; i < HS; i += NT) { hkey[i] = -1; hval[i] = 0; }
    if (tid == 0) { esum_s = 0.f; corr_s = 0.f; lcnt_s = 0; rb_s = 0; pcnt_s = 0; }
    __syncthreads();

    // ---- build penalty-token hash ----
    const int* trow = tokens + (size_t)row * H;
    for (int i = tid; i < H; i += NT) {
        int v = trow[i];
        unsigned h = ((unsigned)v * 2654435761u) >> 23;
        while (true) {
            int prev = atomicCAS(&hkey[h], -1, v);
            if (prev == -1 || prev == v) { atomicAdd(&hval[h], 1); break; }
            h = (h + 1) & HM;
        }
    }

    float t = temps[row];
    float r = __fdiv_rn(1.0f, t);     // same approx everywhere
    float pres = pres_v[row], freq = freq_v[row];
    int active = (pres >= 1e-5f) || (freq >= 1e-5f);
    int k = topk_v[row];
    const float* lrow = logits + (size_t)row * V;
    const float4* l4p = (const float4*)lrow;
    int V4 = V >> 2;
    __syncthreads();

    // ---- Phase S: sampled histogram (~1/16, wave-coalesced chunks) ----
    int S4 = V4 >> 4;
    for (int j = tid; j < S4; j += NT) {
        int c = j >> 6;
        int g = (((c << 4) + (c & 15)) << 6) | (j & 63);   // 64-wide chunks, x16 stride
        if (g < V4) {
            float4 A = l4p[g];
#pragma unroll
            for (int jj = 0; jj < 4; ++jj)
                atomicAdd(&hc[mono_u32(__fmul_rn((&A.x)[jj], r)) >> BSH], 1u);
        }
    }
    __syncthreads();
    float ms = (S4 > 0) ? ((float)k * (float)(S4 << 2) / (float)V) : 0.0f;
    int req = (int)(ms + 8.0f * sqrtf(ms) + 16.0f);
    int bT = (S4 > 0) ? suffix_cut(hc, sct, sct2, req, tid, &cut_s) : 0;
    int thr = bT - 1; if (thr < 0) thr = 0;
    for (int b = tid; b < NB; b += NT) hc[b] = 0u;
    __syncthreads();

    // ---- Phase A: single stream — zero-out + Sexp + sparse hist + compact ----
    float4* o4p = (float4*)(out + (size_t)row * V);
    const float4 z4 = make_float4(0.f, 0.f, 0.f, 0.f);
    float es0 = 0.f, es1 = 0.f, es2 = 0.f, es3 = 0.f;
    int i = tid;
    for (; i + 7 * NT < V4; i += 8 * NT) {
        float4 arr[8];
#pragma unroll
        for (int q = 0; q < 8; ++q) arr[q] = l4p[i + q * NT];
#pragma unroll
        for (int q = 0; q < 8; ++q) o4p[i + q * NT] = z4;
#pragma unroll
        for (int q = 0; q < 8; ++q) {
            int vb = (i + q * NT) << 2;
            float x0 = __fmul_rn(arr[q].x, r), x1 = __fmul_rn(arr[q].y, r);
            float x2 = __fmul_rn(arr[q].z, r), x3 = __fmul_rn(arr[q].w, r);
            es0 += __expf(x0); es1 += __expf(x1); es2 += __expf(x2); es3 += __expf(x3);
            unsigned u0 = mono_u32(x0), u1 = mono_u32(x1);
            unsigned u2 = mono_u32(x2), u3 = mono_u32(x3);
            if ((int)(u0 >> BSH) >= thr) {
                atomicAdd(&hc[u0 >> BSH], 1u);
                int pos = atomicAdd(&lcnt_s, 1);
                if (pos < CAP) skey[pos] = ((ull)u0 << 32) | (unsigned)~(unsigned)(vb);
            }
            if ((int)(u1 >> BSH) >= thr) {
                atomicAdd(&hc[u1 >> BSH], 1u);
                int pos = atomicAdd(&lcnt_s, 1);
                if (pos < CAP) skey[pos] = ((ull)u1 << 32) | (unsigned)~(unsigned)(vb + 1);
            }
            if ((int)(u2 >> BSH) >= thr) {
                atomicAdd(&hc[u2 >> BSH], 1u);
                int pos = atomicAdd(&lcnt_s, 1);
                if (pos < CAP) skey[pos] = ((ull)u2 << 32) | (unsigned)~(unsigned)(vb + 2);
            }
            if ((int)(u3 >> BSH) >= thr) {
                atomicAdd(&hc[u3 >> BSH], 1u);
                int pos = atomicAdd(&lcnt_s, 1);
                if (pos < CAP) skey[pos] = ((ull)u3 << 32) | (unsigned)~(unsigned)(vb + 3);
            }
        }
    }
    for (; i < V4; i += NT) {
        float4 A = l4p[i];
        o4p[i] = z4;
#pragma unroll
        for (int j = 0; j < 4; ++j) {
            float x = __fmul_rn((&A.x)[j], r);
            es0 += __expf(x);
            unsigned u = mono_u32(x);
            if ((int)(u >> BSH) >= thr) {
                atomicAdd(&hc[u >> BSH], 1u);
                int pos = atomicAdd(&lcnt_s, 1);
                if (pos < CAP) skey[pos] = ((ull)u << 32) | (unsigned)~(unsigned)((i << 2) + j);
            }
        }
    }
    for (int v = (V4 << 2) + tid; v < V; v += NT) {
        float x = __fmul_rn(lrow[v], r);
        out[(size_t)row * V + v] = 0.0f;
        es0 += __expf(x);
        unsigned u = mono_u32(x);
        if ((int)(u >> BSH) >= thr) {
            atomicAdd(&hc[u >> BSH], 1u);
            int pos = atomicAdd(&lcnt_s, 1);
            if (pos < CAP) skey[pos] = ((ull)u << 32) | (unsigned)~(unsigned)v;
        }
    }
    float es = (es0 + es1) + (es2 + es3);
    for (int off = 32; off; off >>= 1) es += __shfl_down(es, off);
    if ((tid & 63) == 0) atomicAdd(&esum_s, es);
    __syncthreads();

    // ---- penalty corrections: hist moves + Sexp delta ----
    float corr = 0.0f;
    if (active) {
        for (int s = tid; s < HS; s += NT) {
            int v = hkey[s];
            if (v >= 0) {
                int c = hval[s];
                float l = lrow[v];
                float x0 = __fmul_rn(l, r);
                float xp = compute_x(l, c, pres, freq, t);
                int b0 = (int)(mono_u32(x0) >> BSH);
                int bp = (int)(mono_u32(xp) >> BSH);
                if (b0 != bp) {
                    if (b0 >= thr) atomicSub(&hc[b0], 1u);
                    if (bp >= thr) atomicAdd(&hc[bp], 1u);
                }
                corr += __expf(xp) - __expf(x0);
            }
        }
    }
    for (int off = 32; off; off >>= 1) corr += __shfl_down(corr, off);
    if ((tid & 63) == 0) atomicAdd(&corr_s, corr);
    __syncthreads();
    int lraw = lcnt_s;
    int count = lraw > CAP ? CAP : lraw;

    // ---- key fix-up: exact (penalized) keys for candidates ----
    for (int j = tid; j < count; j += NT) {
        unsigned idx = ~(unsigned)(skey[j] & 0xffffffffull);
        float l = lrow[idx];
        int c = active ? hash_lookup(hkey, hval, (int)idx) : 0;
        unsigned ue = (c > 0) ? mono_u32(compute_x(l, c, pres, freq, t))
                              : mono_u32(__fdiv_rn(l, t));
        skey[j] = ((ull)ue << 32) | (unsigned)~idx;
    }
    __syncthreads();

    int bst = suffix_cut(hc, sct, sct2, k, tid, &cut_s);
    // need 2 buckets of slack: candidates(approx>=thr) must cover exact>=bst-1
    bool ok = (bst >= thr + 2) && (lraw <= CAP);

    if (!ok) {
        // ---- fallback: exact full-histogram path (cold, ~never taken) ----
        for (int b = tid; b < NB; b += NT) hc[b] = 0u;
        if (tid == 0) lcnt_s = 0;
        __syncthreads();
        for (int v = tid; v < V; v += NT)
            atomicAdd(&hc[mono_u32(__fmul_rn(lrow[v], r)) >> BSH], 1u);
        __syncthreads();
        if (active) {
            for (int s = tid; s < HS; s += NT) {
                int v = hkey[s];
                if (v >= 0) {
                    int c = hval[s];
                    float l = lrow[v];
                    int b0 = (int)(mono_u32(__fmul_rn(l, r)) >> BSH);
                    int bp = (int)(mono_u32(compute_x(l, c, pres, freq, t)) >> BSH);
                    if (b0 != bp) { atomicSub(&hc[b0], 1u); atomicAdd(&hc[bp], 1u); }
                }
            }
        }
        __syncthreads();
        bst = suffix_cut(hc, sct, sct2, k, tid, &cut_s);
        int thr2 = bst - 2; if (thr2 < 0) thr2 = 0;
        for (int v = tid; v < V; v += NT) {
            unsigned u = mono_u32(__fmul_rn(lrow[v], r));
            if ((int)(u >> BSH) >= thr2) {
                int pos = atomicAdd(&lcnt_s, 1);
                if (pos < CAP) skey[pos] = ((ull)u << 32) | (unsigned)~(unsigned)v;
            }
        }
        __syncthreads();
        count = lcnt_s > CAP ? CAP : lcnt_s;
        for (int j = tid; j < count; j += NT) {
            unsigned idx = ~(unsigned)(skey[j] & 0xffffffffull);
            float l = lrow[idx];
            int c = active ? hash_lookup(hkey, hval, (int)idx) : 0;
            unsigned ue = (c > 0) ? mono_u32(compute_x(l, c, pres, freq, t))
                                  : mono_u32(__fdiv_rn(l, t));
            skey[j] = ((ull)ue << 32) | (unsigned)~idx;
        }
        __syncthreads();
    }
    float Sp = esum_s + corr_s;

    // ---- Phase D: refined cut on exact keys + prune ----
    for (int g = tid; g < NRB; g += NT) rh[g] = 0u;
    __syncthreads();
    int gmin = (bst - 1) << 6;
    for (int j = tid; j < count; j += NT) {
        unsigned u = (unsigned)(skey[j] >> 32);
        int rel = (int)(u >> RSH) - gmin;
        rel = rel < 0 ? 0 : (rel > NRB - 1 ? NRB - 1 : rel);
        atomicAdd(&rh[rel], 1u);
    }
    __syncthreads();
    {
        int b2i = tid * 2;
        int a2 = (int)rh[b2i + 1];
        rh[b2i + 1] = (unsigned)a2;
        a2 += (int)rh[b2i];
        rh[b2i] = (unsigned)a2;
        sct[tid] = a2;
        __syncthreads();
        int* a = sct; int* b2 = sct2;
        for (int s = 1; s < NT; s <<= 1) {
            int v = a[tid] + ((tid + s < NT) ? a[tid + s] : 0);
            __syncthreads();
            b2[tid] = v;
            __syncthreads();
            int* tmp = a; a = b2; b2 = tmp;
        }
        int above = (tid < NT - 1) ? a[tid + 1] : 0;
        int best = -1;
        if ((int)rh[b2i + 1] + above >= k) best = b2i + 1;
        else if ((int)rh[b2i] + above >= k) best = b2i;
        if (best >= 0) atomicMax(&rb_s, best);
    }
    __syncthreads();
    int rb = rb_s;
    for (int j = tid; j < count; j += NT) {
        unsigned u = (unsigned)(skey[j] >> 32);
        int rel = (int)(u >> RSH) - gmin;
        rel = rel < 0 ? 0 : (rel > NRB - 1 ? NRB - 1 : rel);
        if (rel >= rb) {
            int pos = atomicAdd(&pcnt_s, 1);
            if (pos < PCAP) tmpc[pos] = skey[j];
        }
    }
    __syncthreads();
    int count2 = pcnt_s;
    if (count2 <= PCAP) {   // pruned set is upward-closed in u => rank-preserving
        for (int j = tid; j < count2; j += NT) skey[j] = tmpc[j];
        count = count2;
    }
    __syncthreads();

    // ---- Phase E: bitonic sort descending on (u desc, idx asc) ----
    int m = 1; while (m < count) m <<= 1;
    for (int j = count + tid; j < m; j += NT) skey[j] = 0ull;
    __syncthreads();
    for (int kk = 2; kk <= m; kk <<= 1) {
        for (int jj = kk >> 1; jj > 0; jj >>= 1) {
            for (int i2 = tid; i2 < m; i2 += NT) {
                int ixj = i2 ^ jj;
                if (ixj > i2) {
                    ull A = skey[i2], B = skey[ixj];
                    bool up = ((i2 & kk) != 0);
                    if ((A > B) == up) { skey[i2] = B; skey[ixj] = A; }
                }
            }
            __syncthreads();
        }
    }

    // ---- Phase F: exp, exact cumsum, top-k/top-p select, scatter ----
    for (int j = tid; j < CAP; j += NT)
        se[j] = (j < count) ? __expf(inv_mono((unsigned)(skey[j] >> 32))) : 0.0f;
    __syncthreads();
    int j0 = tid << 3;
    float ee[8], cc[8];
    float run = 0.0f;
#pragma unroll
    for (int q = 0; q < 8; ++q) { ee[q] = se[j0 + q]; run += ee[q]; cc[q] = run; }
    bs1[tid] = run;
    __syncthreads();
    float* a = bs1; float* b2 = bs2;
    for (int s = 1; s < NT; s <<= 1) {
        float v = a[tid] + ((tid >= s) ? a[tid - s] : 0.0f);
        __syncthreads();
        b2[tid] = v;
        __syncthreads();
        float* tmp = a; a = b2; b2 = tmp;
    }
    float pre = (tid > 0) ? a[tid - 1] : 0.0f;

    float pS = topp_v[row] * Sp;
#pragma unroll
    for (int q = 0; q < 8; ++q) {
        int j = j0 + q;
        if (j < count) {
            float e = ee[q];
            float excl = __fsub_rn(pre + cc[q], e);
            if ((j < k) && (excl <= pS)) {
                unsigned idx = ~(unsigned)(skey[j] & 0xffffffffull);
                out[(size_t)row * V + idx] = __fdiv_rn(e, Sp);
            }
        }
    }
}

extern "C" void kernel_launch(void* const* d_in, const int* in_sizes, int n_in,
                              void* d_out, int out_size, void* d_ws, size_t ws_size,
                              hipStream_t stream) {
    const float* logits = (const float*)d_in[0];
    const float* pres   = (const float*)d_in[1];
    const float* freq   = (const float*)d_in[2];
    const float* temps  = (const float*)d_in[3];
    const float* topps  = (const float*)d_in[4];
    const int*   tokens = (const int*)d_in[5];
    const int*   topks  = (const int*)d_in[6];
    int N = in_sizes[1];
    int V = in_sizes[0] / N;
    int H = in_sizes[5] / N;
    float* out = (float*)d_out;

    k_fused<<<N, NT, 0, stream>>>(logits, tokens, pres, freq, temps, topps,
                                  topks, V, H, out);
}